// Round 1
// 343.405 us; speedup vs baseline: 1.0111x; 1.0111x over previous
//
#include <hip/hip_runtime.h>
#include <stdint.h>

#define N_TOTAL 21840
#define NA      21888          // N_TOTAL rounded up to multiple of 64
#define W_MAX   342            // ceil(21840/64)
#define TOT_ENT 3753792u       // 64 * (342*343/2)  triangular CSR capacity
#define NMS_TH  0.3f
#define FINAL_TH 0.5f
#define NSLICE  8              // rank range-split factor
#define SLOTS   11             // CSR slots per row handled by pusher lanes
#define SCAN_T  768            // scan block: 1 scanner wave + 11 pusher waves

struct Inputs { const float* cls[6]; const float* reg[6]; };

// Raw barrier: drains LDS (lgkmcnt) but NOT vmem (vmcnt) — lets prefetched
// global loads stay in flight across the barrier. Only valid when barriers
// order LDS state only (true in scan_kernel: all global inputs read-only).
__device__ __forceinline__ void block_bar() {
  asm volatile("s_waitcnt lgkmcnt(0)\n\ts_barrier" ::: "memory");
}

// Closed-form CSR row base: row r (sorted pos) owns 342-(r>>6) slots.
__device__ __forceinline__ unsigned rowbase_u(unsigned r) {
  unsigned w = r >> 6, l = r & 63u;
  return 64u * (342u * w - (w * (w - 1u)) / 2u) + l * (342u - w);
}

// ---------------------------------------------------------------- decode ----
__global__ void decode_kernel(Inputs in,
                              float* __restrict__ dx1, float* __restrict__ dy1,
                              float* __restrict__ dx2, float* __restrict__ dy2,
                              float* __restrict__ dsc,
                              unsigned long long* __restrict__ ckey,
                              unsigned int* __restrict__ Mc,
                              unsigned int* __restrict__ rank32,
                              unsigned int* __restrict__ cnt,
                              float* __restrict__ out) {
#pragma clang fp contract(off)
  int gid = blockIdx.x * blockDim.x + threadIdx.x;
  if (gid >= N_TOTAL) return;

  rank32[gid] = 0u;                       // zeroed ahead of rank_kernel
  cnt[gid] = 0u;                          // CSR row counts
  if (gid < NA - N_TOTAL) cnt[N_TOTAL + gid] = 0u;   // tail rows

  int sc, local;
  if      (gid < 16384) { sc = 0; local = gid;         }
  else if (gid < 20480) { sc = 1; local = gid - 16384; }
  else if (gid < 21504) { sc = 2; local = gid - 20480; }
  else if (gid < 21760) { sc = 3; local = gid - 21504; }
  else if (gid < 21824) { sc = 4; local = gid - 21760; }
  else                  { sc = 5; local = gid - 21824; }

  const int Wd     = 128 >> sc;
  const int stride = 4 << sc;
  const int HW     = Wd * Wd;
  const int x = local & (Wd - 1);
  const int y = local >> (7 - sc);

  const float* cls = in.cls[sc];
  const float* reg = in.reg[sc];

  float c0 = cls[local];
  float c1 = cls[HW + local];
  float m  = fmaxf(c0, c1);
  float e0 = expf(c0 - m);
  float e1 = expf(c1 - m);
  float prob = e1 / (e0 + e1);

  float l0 = reg[local];
  float l1 = reg[HW + local];
  float l2 = reg[2 * HW + local];
  float l3 = reg[3 * HW + local];

  float sF  = (float)stride;
  float pcx = 0.5f * sF + (float)x * sF;
  float pcy = 0.5f * sF + (float)y * sF;
  float pwh = sF * 4.0f;

  float cx = pcx + ((l0 * 0.1f) * pwh);
  float cy = pcy + ((l1 * 0.1f) * pwh);
  float w  = pwh * expf(l2 * 0.2f);
  float h  = pwh * expf(l3 * 0.2f);
  float x1 = cx - w * 0.5f;
  float y1 = cy - h * 0.5f;
  float x2 = x1 + w;
  float y2 = y1 + h;

  dx1[gid] = x1; dy1[gid] = y1; dx2[gid] = x2; dy2[gid] = y2; dsc[gid] = prob;

  // zero the output row; scan_kernel scatters kept rows afterwards
  out[gid * 5 + 0] = 0.0f;
  out[gid * 5 + 1] = 0.0f;
  out[gid * 5 + 2] = 0.0f;
  out[gid * 5 + 3] = 0.0f;
  out[gid * 5 + 4] = 0.0f;

  // Only boxes with score > FINAL_TH can affect the output (suppression only
  // flows downward in score order, and only >FINAL_TH rows are exposed).
  if (prob > FINAL_TH) {
    unsigned int pos = atomicAdd(Mc, 1u);
    ckey[pos] = ((unsigned long long)__float_as_uint(prob) << 32) |
                (unsigned int)(~(unsigned int)gid);
  }
}

// ---------------------------------------------------------------- rank ------
// Count-rank with 8-way key-range split; packed atomicAdd join.
__global__ void __launch_bounds__(256)
rank_kernel(const unsigned long long* __restrict__ ckey,
            const unsigned int* __restrict__ Mc,
            const float* __restrict__ dx1, const float* __restrict__ dy1,
            const float* __restrict__ dx2, const float* __restrict__ dy2,
            float* __restrict__ sx1, float* __restrict__ sy1,
            float* __restrict__ sx2, float* __restrict__ sy2,
            unsigned int* __restrict__ sorig,
            unsigned int* __restrict__ rank32) {
  __shared__ unsigned long long tile[256];
  const unsigned int M = *Mc;
  if (blockIdx.x * 256u >= M) return;          // uniform per block
  const int t = (int)threadIdx.x;
  const int p = (int)blockIdx.x * 256 + t;
  unsigned long long mykey = (p < (int)M) ? ckey[p] : 0ull;
  const int S  = (int)((M + NSLICE - 1) / NSLICE);
  const int lo = (int)blockIdx.y * S;
  const int hi = min((int)M, lo + S);
  int partial = 0;
  const int nt = (hi > lo) ? ((hi - lo + 255) >> 8) : 0;
  for (int ti = 0; ti < nt; ++ti) {
    int j = lo + ti * 256 + t;
    tile[t] = (j < hi) ? ckey[j] : 0ull;       // 0 never > any real key
    __syncthreads();
#pragma unroll 8
    for (int q = 0; q < 256; ++q) partial += (tile[q] > mykey) ? 1 : 0;
    __syncthreads();
  }
  if (p < (int)M) {
    unsigned int pack = (unsigned int)partial | (1u << 24);
    unsigned int old  = atomicAdd(&rank32[p], pack);
    unsigned int newv = old + pack;
    if ((newv >> 24) == NSLICE) {              // last slice to land scatters
      int r = (int)(newv & 0xFFFFFF);
      unsigned int orig = ~(unsigned int)(mykey & 0xffffffffull);
      sx1[r] = dx1[orig];
      sy1[r] = dy1[orig];
      sx2[r] = dx2[orig];
      sy2[r] = dy2[orig];
      sorig[r] = orig;
    }
  }
}

// ---------------------------------------------------------------- pairs -----
// Sparse suppression structure (COLUMN/transposed forms for the scanner):
//   diag[r]   = FULL symmetric in-word neighborhood of r (scanner lane c
//               masks to bits < c — valid because IoU is symmetric)
//   offdT[r]  = rows of word rw-1 overlapping r  (incoming push, col-form)
//   CSR rows:  rlJw/rlBits[rowbase(r) + k], k < cnt[r], for cw >= rw+2
// The cw == rw+1 band is NOT materialized: it is exactly offdT of block-row
// rw+1, consumed inline by the scanner — must stay out of CSR (race-free).
// 1024-thread blocks: 16 waves = 16 col-words per (row-word) y.
__global__ void __launch_bounds__(1024)
pairs_kernel(const float* __restrict__ sx1, const float* __restrict__ sy1,
             const float* __restrict__ sx2, const float* __restrict__ sy2,
             const unsigned int* __restrict__ Mc,
             unsigned long long* __restrict__ diag,
             unsigned long long* __restrict__ offdT,
             unsigned int* __restrict__ cnt,
             unsigned short* __restrict__ rlJw,
             unsigned long long* __restrict__ rlBits) {
#pragma clang fp contract(off)
  const int M = (int)*Mc;
  const int W = (M + 63) >> 6;
  const int rw = (int)blockIdx.y;
  const int cwg = (int)blockIdx.x << 4;
  if (rw >= W || cwg >= W || cwg + 16 < rw) return;   // need cw >= rw-1

  const int t = (int)threadIdx.x;
  const int g = t >> 6, l = t & 63;
  const int cw = cwg + g;

  __shared__ float cx1[1024], cy1[1024], cx2[1024], cy2[1024], car[1024];
  {
    int c = (cw << 6) + l;
    if (cw < W && c < M) {
      float a = sx1[c], b = sy1[c], d = sx2[c], e = sy2[c];
      cx1[t] = a; cy1[t] = b; cx2[t] = d; cy2[t] = e;
      car[t] = (d - a + 1.0f) * (e - b + 1.0f);
    }
  }
  __syncthreads();
  if (cw >= W || cw + 1 < rw || cw == rw + 1) return;

  const int r = (rw << 6) + l;
  unsigned long long bits = 0ull;
  if (r < M) {
    float ax1 = sx1[r], ay1 = sy1[r], ax2 = sx2[r], ay2 = sy2[r];
    float aarea = (ax2 - ax1 + 1.0f) * (ay2 - ay1 + 1.0f);
    const int cmax = min(64, M - (cw << 6));
    const int sb = g << 6;
    // No cg>r test: diag keeps full symmetric bits (masked at use);
    // offdT band is all-lower; CSR band (cw>=rw+2) is all-higher.
    for (int cc = 0; cc < cmax; ++cc) {
      float xx1 = fmaxf(ax1, cx1[sb + cc]);
      float yy1 = fmaxf(ay1, cy1[sb + cc]);
      float xx2 = fminf(ax2, cx2[sb + cc]);
      float yy2 = fminf(ay2, cy2[sb + cc]);
      float ww = fmaxf(xx2 - xx1 + 1.0f, 0.0f);
      float hh = fmaxf(yy2 - yy1 + 1.0f, 0.0f);
      float inter = ww * hh;
      float iou = inter / (aarea + car[sb + cc] - inter);
      if (iou > NMS_TH) bits |= (1ull << cc);
    }
  }
  if (cw + 1 == rw)        offdT[r] = bits;
  else if (cw == rw)       diag[r]  = bits;
  else if (bits != 0ull) {                       // cw >= rw+2 -> CSR
    unsigned k = atomicAdd(&cnt[r], 1u);
    unsigned b = rowbase_u((unsigned)r) + k;     // capacity 342-rw >= possible
    rlJw[b]   = (unsigned short)cw;
    rlBits[b] = bits;
  }
}

// ---------------------------------------------------------------- scan ------
// Single-block greedy scan over the SPARSE structure. Wave 0 scans word-by-
// word using COLUMN masks only: incoming push = one ballot over
// (offdT & keptPrev), in-word greedy = ballot fixed-point on per-lane column
// blocker masks — zero cross-lane DS ops on the critical chain. Waves 1-11 =
// 704 lanes apply CSR entries (jw >= w+2), 3-deep unpredicated prefetch with
// incremental row-base. ONE barrier per step.
__global__ void __launch_bounds__(SCAN_T)
scan_kernel(const unsigned long long* __restrict__ diag,
            const unsigned long long* __restrict__ offdT,
            const unsigned int* __restrict__ cnt,
            const unsigned short* __restrict__ rlJw,
            const unsigned long long* __restrict__ rlBits,
            const unsigned int* __restrict__ sorig,
            const unsigned int* __restrict__ Mc,
            const float* __restrict__ dx1, const float* __restrict__ dy1,
            const float* __restrict__ dx2, const float* __restrict__ dy2,
            const float* __restrict__ dsc,
            float* __restrict__ out) {
  __shared__ unsigned long long sup[W_MAX];
  __shared__ unsigned long long kmls[W_MAX];
  const int t = (int)threadIdx.x;
  const int g = t >> 6, l = t & 63;
  const int M = (int)*Mc;
  const int W = (M + 63) >> 6;

  for (int i = t; i < W_MAX; i += SCAN_T) { sup[i] = 0ull; kmls[i] = 0ull; }
  block_bar();

  if (g == 0) {
    // -------- scanner wave --------
    const unsigned long long lowm = (1ull << l) - 1ull;  // bits strictly < l
    // 3-deep prefetch of column masks (steps are short vs HBM latency)
    unsigned long long d0 = diag[l] & lowm, o0 = 0ull;   // w=0: no incoming
    unsigned long long d1 = 0ull, o1 = 0ull, d2 = 0ull, o2 = 0ull;
    if (1 < W) { d1 = diag[64 + l] & lowm;  o1 = offdT[64 + l]; }
    if (2 < W) { d2 = diag[128 + l] & lowm; o2 = offdT[128 + l]; }
    unsigned long long keptPrev = 0ull;
    for (int w = 0; w < W; ++w) {
      const int base = w << 6;
      unsigned long long supw = sup[w];
      unsigned long long colmask = d0;       // rows r<l of word w blocking l
      unsigned long long odt = o0;           // rows of word w-1 blocking l
      d0 = d1; o0 = o1; d1 = d2; o1 = o2;
      {   // prefetch word w+3
        int rn = ((w + 3) << 6) + l;
        bool in3 = (w + 3 < W);
        unsigned long long d = in3 ? diag[rn] : 0ull;
        d2 = d & lowm;
        o2 = in3 ? offdT[rn] : 0ull;
      }
      // incoming suppression from kept rows of word w-1 (one ballot)
      unsigned long long incoming = __ballot((odt & keptPrev) != 0ull);
      const int n = min(64, M - base);
      unsigned long long wordmask = (n >= 64) ? ~0ull : ((1ull << n) - 1ull);
      unsigned long long pend = (~(supw | incoming)) & wordmask;
      // in-word greedy: ballot fixed-point. Lane l kept iff active and no
      // kept blocker in colmask. Lowest undecided lane always decides ->
      // guaranteed progress; rounds = in-word chain depth (typ. 1-2).
      unsigned long long kept = 0ull;
      unsigned long long dead = ~pend;       // confirmed not-kept
      unsigned long long und  = pend;
      while (und) {
        unsigned long long bSup  = __ballot((colmask & kept) != 0ull) & und;
        unsigned long long bKept = __ballot((colmask & ~dead) == 0ull) & und;
        kept |= bKept;
        dead |= bSup;
        und  &= ~(bKept | bSup);
      }
      if (l == 0) kmls[w] = kept;
      keptPrev = kept;
      block_bar();
    }
  } else {
    // -------- pusher lanes: 704 = 64 rows x 11 slots --------
    const int p = (g - 1) * 64 + l;
    const int jrow = p / SLOTS;          // row within word, 0..63
    const int sub  = p % SLOTS;          // CSR slot 0..SLOTS-1
    unsigned c0, c1, c2;                 // cnt pipeline (w .. w+2)
    unsigned long long b0, b1, b2;       // bits pipeline (w .. w+2)
    unsigned j0, j1, j2;                 // jw pipeline
    unsigned rbase;                      // rowbase(word w+3, jrow) + sub
    {   // prologue: unpredicated clamped loads (garbage unused: apply is
        // predicated by sub < cnt, and valid slots always hold real data)
      c0 = cnt[jrow];
      c1 = (1 < W) ? cnt[64 + jrow] : 0u;
      c2 = (2 < W) ? cnt[128 + jrow] : 0u;
      unsigned i;
      i = rowbase_u((unsigned)jrow) + sub;         if (i >= TOT_ENT) i = 0;
      b0 = rlBits[i]; j0 = rlJw[i];
      i = rowbase_u((unsigned)(64 + jrow)) + sub;  if (i >= TOT_ENT) i = 0;
      b1 = rlBits[i]; j1 = rlJw[i];
      i = rowbase_u((unsigned)(128 + jrow)) + sub; if (i >= TOT_ENT) i = 0;
      b2 = rlBits[i]; j2 = rlJw[i];
      rbase = rowbase_u((unsigned)(192 + jrow)) + sub;   // v = 3
    }
    for (int w = 0; w < W; ++w) {
      block_bar();
      const unsigned long long km = kmls[w];
      if ((km >> jrow) & 1ull) {
        if (sub < (int)c0) atomicOr(&sup[j0], b0);
        if (c0 > (unsigned)SLOTS) {      // rare high-degree tail
          unsigned rb_ = rowbase_u((unsigned)(w * 64 + jrow));
          for (int k = sub + SLOTS; k < (int)c0; k += SLOTS) {
            unsigned ii = rb_ + k;
            atomicOr(&sup[rlJw[ii]], rlBits[ii]);
          }
        }
      }
      // rotate pipelines
      c0 = c1; c1 = c2;
      b0 = b1; j0 = j1; b1 = b2; j1 = j2;
      // issue loads for word w+3 (incremental row base, no cnt predicate)
      {
        int w3 = w + 3;
        bool in3 = (w3 < W);
        unsigned i = rbase;
        if (i >= TOT_ENT) i = 0;
        c2 = in3 ? cnt[w3 * 64 + jrow] : 0u;
        b2 = in3 ? rlBits[i] : 0ull;
        j2 = in3 ? (unsigned)rlJw[i] : 0u;
        // advance rowbase word v=w+3 -> v+1: delta = 64*(342-v) - jrow
        rbase += (unsigned)(64 * (339 - w) - jrow);
      }
    }
  }
  block_bar();

  // scatter kept rows into the (pre-zeroed) output
  for (int i = t; i < (W << 6); i += SCAN_T) {
    if ((kmls[i >> 6] >> (i & 63)) & 1ull) {
      unsigned int orig = sorig[i];
      out[(size_t)orig * 5 + 0] = dx1[orig];
      out[(size_t)orig * 5 + 1] = dy1[orig];
      out[(size_t)orig * 5 + 2] = dx2[orig];
      out[(size_t)orig * 5 + 3] = dy2[orig];
      out[(size_t)orig * 5 + 4] = dsc[orig];
    }
  }
}

// ------------------------------------------------- fallback NMS (tiny ws) ---
__global__ void __launch_bounds__(1024)
nms_kernel(const float* __restrict__ sx1, const float* __restrict__ sy1,
           const float* __restrict__ sx2, const float* __restrict__ sy2,
           const unsigned int* __restrict__ sorig,
           const unsigned int* __restrict__ Mc,
           unsigned int* __restrict__ keepflag) {
#pragma clang fp contract(off)
  __shared__ unsigned long long sup[W_MAX];
  __shared__ unsigned long long inrow[64];
  __shared__ float wx1[64], wy1[64], wx2[64], wy2[64], warea[64];
  __shared__ unsigned long long keptmask_sh;

  const int t = (int)threadIdx.x;
  const int M = (int)*Mc;
  const int W = (M + 63) >> 6;

  for (int i = t; i < W_MAX; i += 1024) sup[i] = 0ull;
  __syncthreads();

  for (int w = 0; w < W; ++w) {
    const int base = w << 6;
    const int n = min(64, M - base);
    if (t < 64) {
      if (t < n) {
        float a = sx1[base + t], b = sy1[base + t];
        float c = sx2[base + t], d = sy2[base + t];
        wx1[t] = a; wy1[t] = b; wx2[t] = c; wy2[t] = d;
        warea[t] = (c - a + 1.0f) * (d - b + 1.0f);
      }
    } else if (t < 128) {
      inrow[t - 64] = 0ull;
    }
    __syncthreads();
    {
      int r = t & 63, seg = t >> 6;
      unsigned long long bits = 0ull;
      if (r < n) {
        float ax1 = wx1[r], ay1 = wy1[r], ax2 = wx2[r], ay2 = wy2[r];
        float aarea = warea[r];
        for (int c = seg * 4; c < seg * 4 + 4; ++c) {
          if (c > r && c < n) {
            float xx1 = fmaxf(ax1, wx1[c]);
            float yy1 = fmaxf(ay1, wy1[c]);
            float xx2 = fminf(ax2, wx2[c]);
            float yy2 = fminf(ay2, wy2[c]);
            float ww = fmaxf(xx2 - xx1 + 1.0f, 0.0f);
            float hh = fmaxf(yy2 - yy1 + 1.0f, 0.0f);
            float inter = ww * hh;
            float iou = inter / (aarea + warea[c] - inter);
            if (iou > NMS_TH) bits |= (1ull << c);
          }
        }
      }
      if (bits) atomicOr(&inrow[r], bits);
    }
    __syncthreads();
    if (t < 64) {
      unsigned long long wordmask = (n >= 64) ? ~0ull : ((1ull << n) - 1ull);
      unsigned long long pending = (~sup[w]) & wordmask;
      unsigned long long kept = 0ull;
      while (pending) {
        int i = __builtin_ctzll(pending);
        kept |= (1ull << i);
        pending &= ~(inrow[i] | (1ull << i));
      }
      if (t == 0) keptmask_sh = kept;
      if (t < n && ((kept >> t) & 1ull)) keepflag[sorig[base + t]] = 1u;
    }
    __syncthreads();
    unsigned long long km = keptmask_sh;
    if (km) {
      int wid = t >> 6, lane = t & 63;
      for (int jw = w + 1 + wid; (jw << 6) < M; jw += 16) {
        int j = (jw << 6) + lane;
        bool supj = false;
        if (j < M) {
          float jx1 = sx1[j], jy1 = sy1[j], jx2 = sx2[j], jy2 = sy2[j];
          float jarea = (jx2 - jx1 + 1.0f) * (jy2 - jy1 + 1.0f);
          unsigned long long mm = km;
          while (mm) {
            int r = __builtin_ctzll(mm);
            mm &= mm - 1ull;
            float xx1 = fmaxf(wx1[r], jx1);
            float yy1 = fmaxf(wy1[r], jy1);
            float xx2 = fminf(wx2[r], jx2);
            float yy2 = fminf(wy2[r], jy2);
            float ww = fmaxf(xx2 - xx1 + 1.0f, 0.0f);
            float hh = fmaxf(yy2 - yy1 + 1.0f, 0.0f);
            float inter = ww * hh;
            float iou = inter / (warea[r] + jarea - inter);
            if (iou > NMS_TH) { supj = true; break; }
          }
        }
        unsigned long long bal = __ballot(supj);
        if (lane == 0 && bal) atomicOr(&sup[jw], bal);
      }
    }
    __syncthreads();
  }
}

// ---------------------------------------------------------------- output ----
// (fallback path only)
__global__ void output_kernel(const float* __restrict__ dx1, const float* __restrict__ dy1,
                              const float* __restrict__ dx2, const float* __restrict__ dy2,
                              const float* __restrict__ dsc,
                              const unsigned int* __restrict__ keepflag,
                              float* __restrict__ out) {
#pragma clang fp contract(off)
  int gid = blockIdx.x * blockDim.x + threadIdx.x;
  if (gid >= N_TOTAL) return;
  float f = keepflag[gid] ? 1.0f : 0.0f;
  out[gid * 5 + 0] = dx1[gid] * f;
  out[gid * 5 + 1] = dy1[gid] * f;
  out[gid * 5 + 2] = dx2[gid] * f;
  out[gid * 5 + 3] = dy2[gid] * f;
  out[gid * 5 + 4] = dsc[gid] * f;
}

// ---------------------------------------------------------------- launch ----
extern "C" void kernel_launch(void* const* d_in, const int* in_sizes, int n_in,
                              void* d_out, int out_size, void* d_ws, size_t ws_size,
                              hipStream_t stream) {
  (void)in_sizes; (void)n_in; (void)out_size;

  Inputs in;
  for (int i = 0; i < 6; ++i) {
    in.cls[i] = (const float*)d_in[2 * i];
    in.reg[i] = (const float*)d_in[2 * i + 1];
  }

  char* ws = (char*)d_ws;
  size_t o = 0;
  float* dx1 = (float*)(ws + o); o += (size_t)NA * 4;
  float* dy1 = (float*)(ws + o); o += (size_t)NA * 4;
  float* dx2 = (float*)(ws + o); o += (size_t)NA * 4;
  float* dy2 = (float*)(ws + o); o += (size_t)NA * 4;
  float* dsc = (float*)(ws + o); o += (size_t)NA * 4;
  unsigned long long* ckey = (unsigned long long*)(ws + o); o += (size_t)NA * 8;
  float* sx1 = (float*)(ws + o); o += (size_t)NA * 4;
  float* sy1 = (float*)(ws + o); o += (size_t)NA * 4;
  float* sx2 = (float*)(ws + o); o += (size_t)NA * 4;
  float* sy2 = (float*)(ws + o); o += (size_t)NA * 4;
  unsigned int* sorig = (unsigned int*)(ws + o); o += (size_t)NA * 4;
  unsigned int* keepflag = (unsigned int*)(ws + o); o += (size_t)NA * 4;
  unsigned int* rank32 = (unsigned int*)(ws + o); o += (size_t)NA * 4;
  unsigned int* cnt = (unsigned int*)(ws + o); o += (size_t)NA * 4;
  unsigned int* Mc = (unsigned int*)(ws + o); o += 64;
  o = (o + 511) & ~(size_t)511;
  unsigned long long* diag = (unsigned long long*)(ws + o); o += (size_t)NA * 8;
  unsigned long long* offdT = (unsigned long long*)(ws + o); o += (size_t)NA * 8;
  unsigned long long* rlBits = (unsigned long long*)(ws + o); o += (size_t)TOT_ENT * 8;
  unsigned short* rlJw = (unsigned short*)(ws + o); o += (size_t)TOT_ENT * 2;
  size_t need = o;                            // ~40 MiB
  const bool fast = (need <= ws_size);        // ws_size constant -> graph-safe

  const int nb = (N_TOTAL + 255) / 256;  // 86

  if (fast) {
    (void)hipMemsetAsync((void*)Mc, 0, 64, stream);
    decode_kernel<<<nb, 256, 0, stream>>>(in, dx1, dy1, dx2, dy2, dsc, ckey, Mc,
                                          rank32, cnt, (float*)d_out);
    rank_kernel<<<dim3(nb, NSLICE), 256, 0, stream>>>(ckey, Mc, dx1, dy1, dx2, dy2,
                                                      sx1, sy1, sx2, sy2, sorig,
                                                      rank32);
    pairs_kernel<<<dim3(22, W_MAX), 1024, 0, stream>>>(sx1, sy1, sx2, sy2, Mc,
                                                       diag, offdT, cnt, rlJw, rlBits);
    scan_kernel<<<1, SCAN_T, 0, stream>>>(diag, offdT, cnt, rlJw, rlBits, sorig, Mc,
                                          dx1, dy1, dx2, dy2, dsc, (float*)d_out);
  } else {
    // fallback: zero keepflag + rank32 + cnt + Mc (contiguous)
    (void)hipMemsetAsync((void*)keepflag, 0, (size_t)NA * 12 + 64, stream);
    decode_kernel<<<nb, 256, 0, stream>>>(in, dx1, dy1, dx2, dy2, dsc, ckey, Mc,
                                          rank32, cnt, (float*)d_out);
    rank_kernel<<<dim3(nb, NSLICE), 256, 0, stream>>>(ckey, Mc, dx1, dy1, dx2, dy2,
                                                      sx1, sy1, sx2, sy2, sorig,
                                                      rank32);
    nms_kernel<<<1, 1024, 0, stream>>>(sx1, sy1, sx2, sy2, sorig, Mc, keepflag);
    output_kernel<<<nb, 256, 0, stream>>>(dx1, dy1, dx2, dy2, dsc, keepflag,
                                          (float*)d_out);
  }
}

// Round 2
// 262.084 us; speedup vs baseline: 1.3249x; 1.3103x over previous
//
#include <hip/hip_runtime.h>
#include <stdint.h>

#define N_TOTAL 21840
#define NA      21888          // N_TOTAL rounded up to multiple of 64
#define W_MAX   342            // ceil(21840/64)
#define TOT_ENT 3753792u       // 64 * (342*343/2)  triangular CSR capacity
#define NMS_TH  0.3f
#define FINAL_TH 0.5f
#define NSLICE  8              // rank range-split factor
#define SLOTS   11             // CSR slots per row handled by pusher lanes
#define SCAN_T  768            // scan block: 1 scanner wave + 11 pusher waves
#define GRP     4              // words per barrier step (group size)
#define NBAND   7              // 2*GRP-1 transposed band arrays

struct Inputs { const float* cls[6]; const float* reg[6]; };

// Raw barrier: drains LDS (lgkmcnt) but NOT vmem (vmcnt) — lets prefetched
// global loads stay in flight across the barrier. Only valid when barriers
// order LDS state only (true in scan_kernel: all global inputs read-only).
__device__ __forceinline__ void block_bar() {
  asm volatile("s_waitcnt lgkmcnt(0)\n\ts_barrier" ::: "memory");
}

// Closed-form CSR row base: row r (sorted pos) owns 342-(r>>6) slots.
__device__ __forceinline__ unsigned rowbase_u(unsigned r) {
  unsigned w = r >> 6, l = r & 63u;
  return 64u * (342u * w - (w * (w - 1u)) / 2u) + l * (342u - w);
}

// ---------------------------------------------------------------- decode ----
__global__ void decode_kernel(Inputs in,
                              float* __restrict__ dx1, float* __restrict__ dy1,
                              float* __restrict__ dx2, float* __restrict__ dy2,
                              float* __restrict__ dsc,
                              unsigned long long* __restrict__ ckey,
                              unsigned int* __restrict__ Mc,
                              unsigned int* __restrict__ rank32,
                              unsigned int* __restrict__ cnt,
                              float* __restrict__ out) {
#pragma clang fp contract(off)
  int gid = blockIdx.x * blockDim.x + threadIdx.x;
  if (gid >= N_TOTAL) return;

  rank32[gid] = 0u;                       // zeroed ahead of rank_kernel
  cnt[gid] = 0u;                          // CSR row counts
  if (gid < NA - N_TOTAL) cnt[N_TOTAL + gid] = 0u;   // tail rows

  int sc, local;
  if      (gid < 16384) { sc = 0; local = gid;         }
  else if (gid < 20480) { sc = 1; local = gid - 16384; }
  else if (gid < 21504) { sc = 2; local = gid - 20480; }
  else if (gid < 21760) { sc = 3; local = gid - 21504; }
  else if (gid < 21824) { sc = 4; local = gid - 21760; }
  else                  { sc = 5; local = gid - 21824; }

  const int Wd     = 128 >> sc;
  const int stride = 4 << sc;
  const int HW     = Wd * Wd;
  const int x = local & (Wd - 1);
  const int y = local >> (7 - sc);

  const float* cls = in.cls[sc];
  const float* reg = in.reg[sc];

  float c0 = cls[local];
  float c1 = cls[HW + local];
  float m  = fmaxf(c0, c1);
  float e0 = expf(c0 - m);
  float e1 = expf(c1 - m);
  float prob = e1 / (e0 + e1);

  float l0 = reg[local];
  float l1 = reg[HW + local];
  float l2 = reg[2 * HW + local];
  float l3 = reg[3 * HW + local];

  float sF  = (float)stride;
  float pcx = 0.5f * sF + (float)x * sF;
  float pcy = 0.5f * sF + (float)y * sF;
  float pwh = sF * 4.0f;

  float cx = pcx + ((l0 * 0.1f) * pwh);
  float cy = pcy + ((l1 * 0.1f) * pwh);
  float w  = pwh * expf(l2 * 0.2f);
  float h  = pwh * expf(l3 * 0.2f);
  float x1 = cx - w * 0.5f;
  float y1 = cy - h * 0.5f;
  float x2 = x1 + w;
  float y2 = y1 + h;

  dx1[gid] = x1; dy1[gid] = y1; dx2[gid] = x2; dy2[gid] = y2; dsc[gid] = prob;

  // zero the output row; scan_kernel scatters kept rows afterwards
  out[gid * 5 + 0] = 0.0f;
  out[gid * 5 + 1] = 0.0f;
  out[gid * 5 + 2] = 0.0f;
  out[gid * 5 + 3] = 0.0f;
  out[gid * 5 + 4] = 0.0f;

  // Only boxes with score > FINAL_TH can affect the output (suppression only
  // flows downward in score order, and only >FINAL_TH rows are exposed).
  if (prob > FINAL_TH) {
    unsigned int pos = atomicAdd(Mc, 1u);
    ckey[pos] = ((unsigned long long)__float_as_uint(prob) << 32) |
                (unsigned int)(~(unsigned int)gid);
  }
}

// ---------------------------------------------------------------- rank ------
// Count-rank with 8-way key-range split; packed atomicAdd join.
__global__ void __launch_bounds__(256)
rank_kernel(const unsigned long long* __restrict__ ckey,
            const unsigned int* __restrict__ Mc,
            const float* __restrict__ dx1, const float* __restrict__ dy1,
            const float* __restrict__ dx2, const float* __restrict__ dy2,
            float* __restrict__ sx1, float* __restrict__ sy1,
            float* __restrict__ sx2, float* __restrict__ sy2,
            unsigned int* __restrict__ sorig,
            unsigned int* __restrict__ rank32) {
  __shared__ unsigned long long tile[256];
  const unsigned int M = *Mc;
  if (blockIdx.x * 256u >= M) return;          // uniform per block
  const int t = (int)threadIdx.x;
  const int p = (int)blockIdx.x * 256 + t;
  unsigned long long mykey = (p < (int)M) ? ckey[p] : 0ull;
  const int S  = (int)((M + NSLICE - 1) / NSLICE);
  const int lo = (int)blockIdx.y * S;
  const int hi = min((int)M, lo + S);
  int partial = 0;
  const int nt = (hi > lo) ? ((hi - lo + 255) >> 8) : 0;
  for (int ti = 0; ti < nt; ++ti) {
    int j = lo + ti * 256 + t;
    tile[t] = (j < hi) ? ckey[j] : 0ull;       // 0 never > any real key
    __syncthreads();
#pragma unroll 8
    for (int q = 0; q < 256; ++q) partial += (tile[q] > mykey) ? 1 : 0;
    __syncthreads();
  }
  if (p < (int)M) {
    unsigned int pack = (unsigned int)partial | (1u << 24);
    unsigned int old  = atomicAdd(&rank32[p], pack);
    unsigned int newv = old + pack;
    if ((newv >> 24) == NSLICE) {              // last slice to land scatters
      int r = (int)(newv & 0xFFFFFF);
      unsigned int orig = ~(unsigned int)(mykey & 0xffffffffull);
      sx1[r] = dx1[orig];
      sy1[r] = dy1[orig];
      sx2[r] = dx2[orig];
      sy2[r] = dy2[orig];
      sorig[r] = orig;
    }
  }
}

// ---------------------------------------------------------------- pairs -----
// Sparse suppression structure for GROUPED scan (group = GRP words):
//   diag[r]        = FULL symmetric in-word neighborhood of r (masked at use)
//   bandT[d-1][r]  = boxes of word (rw-d) overlapping box r, d = 1..7,
//                    materialized iff group(rw-d) >= group(rw)-1 (else unused)
//   CSR rows       = rlJw/rlBits[rowbase(r)+k], k < cnt[r], for
//                    group(cw) >= group(rw)+2 ONLY (inline bands cover rest)
// The skip zone (cw > rw, group(cw) <= group(rw)+1) is handled transposed by
// the block with roles swapped — must stay out of CSR (race-free at group
// granularity). 1024-thread blocks: 16 waves = 16 col-words per row-word y.
__global__ void __launch_bounds__(1024)
pairs_kernel(const float* __restrict__ sx1, const float* __restrict__ sy1,
             const float* __restrict__ sx2, const float* __restrict__ sy2,
             const unsigned int* __restrict__ Mc,
             unsigned long long* __restrict__ diag,
             unsigned long long* __restrict__ bandT,
             unsigned int* __restrict__ cnt,
             unsigned short* __restrict__ rlJw,
             unsigned long long* __restrict__ rlBits) {
#pragma clang fp contract(off)
  const int M = (int)*Mc;
  const int W = (M + 63) >> 6;
  const int rw = (int)blockIdx.y;
  const int cwg = (int)blockIdx.x << 4;
  if (rw >= W || cwg >= W || cwg + 22 < rw) return;   // need cw >= rw-7

  const int t = (int)threadIdx.x;
  const int g = t >> 6, l = t & 63;
  const int cw = cwg + g;

  __shared__ float cx1[1024], cy1[1024], cx2[1024], cy2[1024], car[1024];
  {
    int c = (cw << 6) + l;
    if (cw < W && c < M) {
      float a = sx1[c], b = sy1[c], d = sx2[c], e = sy2[c];
      cx1[t] = a; cy1[t] = b; cx2[t] = d; cy2[t] = e;
      car[t] = (d - a + 1.0f) * (e - b + 1.0f);
    }
  }
  __syncthreads();
  if (cw >= W) return;
  const int rwg = rw >> 2, cg = cw >> 2;
  const bool isDiag = (cw == rw);
  const bool isBand = (cw < rw) && (cg >= rwg - 1);
  const bool isCsr  = (cg >= rwg + 2);
  if (!isDiag && !isBand && !isCsr) return;

  const int r = (rw << 6) + l;
  unsigned long long bits = 0ull;
  if (r < M) {
    float ax1 = sx1[r], ay1 = sy1[r], ax2 = sx2[r], ay2 = sy2[r];
    float aarea = (ax2 - ax1 + 1.0f) * (ay2 - ay1 + 1.0f);
    const int cmax = min(64, M - (cw << 6));
    const int sb = g << 6;
    // No cg>r test: diag keeps full symmetric bits (masked at use);
    // band zone is all-lower; CSR zone is all-higher.
    for (int cc = 0; cc < cmax; ++cc) {
      float xx1 = fmaxf(ax1, cx1[sb + cc]);
      float yy1 = fmaxf(ay1, cy1[sb + cc]);
      float xx2 = fminf(ax2, cx2[sb + cc]);
      float yy2 = fminf(ay2, cy2[sb + cc]);
      float ww = fmaxf(xx2 - xx1 + 1.0f, 0.0f);
      float hh = fmaxf(yy2 - yy1 + 1.0f, 0.0f);
      float inter = ww * hh;
      float iou = inter / (aarea + car[sb + cc] - inter);
      if (iou > NMS_TH) bits |= (1ull << cc);
    }
  }
  if (isDiag)      diag[r] = bits;
  else if (isBand) bandT[(size_t)(rw - cw - 1) * NA + r] = bits;
  else if (bits != 0ull) {                       // CSR: group dist >= 2
    unsigned k = atomicAdd(&cnt[r], 1u);
    unsigned b = rowbase_u((unsigned)r) + k;     // capacity 342-rw suffices
    rlJw[b]   = (unsigned short)cw;
    rlBits[b] = bits;
  }
}

// ---------------------------------------------------------------- scan ------
// Single-block greedy scan, GRP=4 words per barrier step (43 steps instead of
// 171 — the fixed per-step latency [barrier + LDS round-trips] dominated at
// word granularity; grouping amortizes it 4x). Wave 0 resolves the 4 words
// serially in registers: incoming = ONE ballot per word over OR of band&src
// products (sources = kept masks of current + previous group, all uniform
// from ballots); in-word greedy = ballot fixed-point. Waves 1-11 apply CSR
// entries (group dist >= 2) for 4 words/step, depth-2 group prefetch with
// clamped unconditional addresses. ONE barrier per step.
__global__ void __launch_bounds__(SCAN_T)
scan_kernel(const unsigned long long* __restrict__ diag,
            const unsigned long long* __restrict__ bandT,
            const unsigned int* __restrict__ cnt,
            const unsigned short* __restrict__ rlJw,
            const unsigned long long* __restrict__ rlBits,
            const unsigned int* __restrict__ sorig,
            const unsigned int* __restrict__ Mc,
            const float* __restrict__ dx1, const float* __restrict__ dy1,
            const float* __restrict__ dx2, const float* __restrict__ dy2,
            const float* __restrict__ dsc,
            float* __restrict__ out) {
  __shared__ unsigned long long sup[W_MAX];
  __shared__ unsigned long long kmls[W_MAX];
  const int t = (int)threadIdx.x;
  const int g = t >> 6, l = t & 63;
  const int M = (int)*Mc;
  const int W = (M + 63) >> 6;
  const int NS = (W + 3) >> 2;

  for (int i = t; i < W_MAX; i += SCAN_T) { sup[i] = 0ull; kmls[i] = 0ull; }
  block_bar();

  if (g == 0) {
    // -------- scanner wave --------
    const unsigned long long lowm = (1ull << l) - 1ull;  // bits strictly < l
    unsigned long long dc[4], dn[4];         // diag, current / next group
    unsigned long long bc[4][NBAND], bn[4][NBAND];   // bands (d<=i+4 only)
    unsigned long long kp[4] = {0ull, 0ull, 0ull, 0ull}, kc[4];
    // prologue: group 0 -> cur, group 1 -> next. Clamped addresses (no
    // value-dependent selects -> loads issue without waits; masked at use).
#pragma unroll
    for (int i = 0; i < 4; ++i) {
      int v = i, vc = (v < W) ? v : 0;
      dc[i] = diag[(vc << 6) + l];
#pragma unroll
      for (int d = 1; d <= NBAND; ++d)
        if (d <= i + 4) bc[i][d - 1] = bandT[(size_t)(d - 1) * NA + (vc << 6) + l];
    }
#pragma unroll
    for (int i = 0; i < 4; ++i) {
      int v = 4 + i, vc = (v < W) ? v : 0;
      dn[i] = diag[(vc << 6) + l];
#pragma unroll
      for (int d = 1; d <= NBAND; ++d)
        if (d <= i + 4) bn[i][d - 1] = bandT[(size_t)(d - 1) * NA + (vc << 6) + l];
    }
    for (int s = 0; s < NS; ++s) {
      const int v0 = s << 2;
      unsigned long long sv[4];
#pragma unroll
      for (int i = 0; i < 4; ++i)
        sv[i] = (v0 + i < W) ? sup[v0 + i] : 0ull;
#pragma unroll
      for (int i = 0; i < 4; ++i) {
        const int v = v0 + i;
        unsigned long long kept = 0ull;
        if (v < W) {
          // incoming suppression from words v-1..v-(i+4) (group dist <= 1):
          // src masks are uniform ballot results; garbage bands (u<0 at s=0)
          // are ANDed with kp[...]=0. ONE ballot total.
          unsigned long long acc = 0ull;
#pragma unroll
          for (int d = 1; d <= NBAND; ++d)
            if (d <= i + 4) {
              unsigned long long src = (d <= i) ? kc[i - d] : kp[i - d + 4];
              acc |= (bc[i][d - 1] & src);
            }
          unsigned long long incoming = __ballot(acc != 0ull);
          const int n = min(64, M - (v << 6));
          unsigned long long wm = (n >= 64) ? ~0ull : ((1ull << n) - 1ull);
          unsigned long long pend = (~(sv[i] | incoming)) & wm;
          // in-word greedy: ballot fixed-point (lowest undecided lane always
          // decides each round -> guaranteed progress, typ. 1-2 rounds)
          const unsigned long long dv = dc[i] & lowm;
          unsigned long long dead = ~pend, und = pend;
          while (und) {
            unsigned long long bS = __ballot((dv & kept) != 0ull) & und;
            unsigned long long bK = __ballot((dv & ~dead) == 0ull) & und;
            kept |= bK; dead |= bS; und &= ~(bK | bS);
          }
          if (l == i) kmls[v] = kept;
        }
        kc[i] = kept;
      }
      // rotate pipelines; issue loads for group s+2
#pragma unroll
      for (int i = 0; i < 4; ++i) kp[i] = kc[i];
#pragma unroll
      for (int i = 0; i < 4; ++i) {
        dc[i] = dn[i];
#pragma unroll
        for (int d = 0; d < NBAND; ++d)
          if (d <= i + 3) bc[i][d] = bn[i][d];
      }
      const int vn = v0 + 8;
#pragma unroll
      for (int i = 0; i < 4; ++i) {
        int v = vn + i, vc = (v < W) ? v : 0;
        dn[i] = diag[(vc << 6) + l];
#pragma unroll
        for (int d = 1; d <= NBAND; ++d)
          if (d <= i + 4) bn[i][d - 1] = bandT[(size_t)(d - 1) * NA + (vc << 6) + l];
      }
      block_bar();
    }
  } else {
    // -------- pusher lanes: 704 = 64 rows x 11 slots, 4 words per step -----
    const int p = (g - 1) * 64 + l;
    const int jrow = p / SLOTS;          // row within word, 0..63
    const int sub  = p % SLOTS;          // CSR slot 0..SLOTS-1
    unsigned cc[4], nc[4];               // cnt, current / next group
    unsigned long long cb[4], nb[4];     // bits
    unsigned cj[4], nj[4];               // jw
    // prologue: group 0 -> cur, group 1 -> next (clamped, unpredicated;
    // garbage unused: apply is predicated by jrow-kept and sub < cnt)
#pragma unroll
    for (int i = 0; i < 4; ++i) {
      int w = i, wc = (w < W) ? w : 0;
      cc[i] = cnt[(wc << 6) + jrow];
      unsigned idx = rowbase_u((unsigned)((wc << 6) + jrow)) + sub;
      if (idx >= TOT_ENT) idx = 0;
      cb[i] = rlBits[idx]; cj[i] = (unsigned)rlJw[idx];
    }
#pragma unroll
    for (int i = 0; i < 4; ++i) {
      int w = 4 + i, wc = (w < W) ? w : 0;
      nc[i] = cnt[(wc << 6) + jrow];
      unsigned idx = rowbase_u((unsigned)((wc << 6) + jrow)) + sub;
      if (idx >= TOT_ENT) idx = 0;
      nb[i] = rlBits[idx]; nj[i] = (unsigned)rlJw[idx];
    }
    for (int s = 0; s < NS; ++s) {
      block_bar();
      const int v0 = s << 2;
#pragma unroll
      for (int i = 0; i < 4; ++i) {
        const int w = v0 + i;
        const unsigned long long km = (w < W) ? kmls[w] : 0ull;
        if ((km >> jrow) & 1ull) {
          if (sub < (int)cc[i]) atomicOr(&sup[cj[i]], cb[i]);
          if (cc[i] > (unsigned)SLOTS) {   // rare high-degree tail
            unsigned rb_ = rowbase_u((unsigned)((w << 6) + jrow));
            for (int k = sub + SLOTS; k < (int)cc[i]; k += SLOTS) {
              unsigned ii2 = rb_ + k;
              atomicOr(&sup[rlJw[ii2]], rlBits[ii2]);
            }
          }
        }
      }
      // rotate; issue loads for group s+2
#pragma unroll
      for (int i = 0; i < 4; ++i) { cc[i] = nc[i]; cb[i] = nb[i]; cj[i] = nj[i]; }
      const int w0 = v0 + 8;
#pragma unroll
      for (int i = 0; i < 4; ++i) {
        int w = w0 + i, wc = (w < W) ? w : 0;
        nc[i] = cnt[(wc << 6) + jrow];
        unsigned idx = rowbase_u((unsigned)((wc << 6) + jrow)) + sub;
        if (idx >= TOT_ENT) idx = 0;
        nb[i] = rlBits[idx]; nj[i] = (unsigned)rlJw[idx];
      }
    }
  }
  block_bar();

  // scatter kept rows into the (pre-zeroed) output
  for (int i = t; i < (W << 6); i += SCAN_T) {
    if ((kmls[i >> 6] >> (i & 63)) & 1ull) {
      unsigned int orig = sorig[i];
      out[(size_t)orig * 5 + 0] = dx1[orig];
      out[(size_t)orig * 5 + 1] = dy1[orig];
      out[(size_t)orig * 5 + 2] = dx2[orig];
      out[(size_t)orig * 5 + 3] = dy2[orig];
      out[(size_t)orig * 5 + 4] = dsc[orig];
    }
  }
}

// ------------------------------------------------- fallback NMS (tiny ws) ---
__global__ void __launch_bounds__(1024)
nms_kernel(const float* __restrict__ sx1, const float* __restrict__ sy1,
           const float* __restrict__ sx2, const float* __restrict__ sy2,
           const unsigned int* __restrict__ sorig,
           const unsigned int* __restrict__ Mc,
           unsigned int* __restrict__ keepflag) {
#pragma clang fp contract(off)
  __shared__ unsigned long long sup[W_MAX];
  __shared__ unsigned long long inrow[64];
  __shared__ float wx1[64], wy1[64], wx2[64], wy2[64], warea[64];
  __shared__ unsigned long long keptmask_sh;

  const int t = (int)threadIdx.x;
  const int M = (int)*Mc;
  const int W = (M + 63) >> 6;

  for (int i = t; i < W_MAX; i += 1024) sup[i] = 0ull;
  __syncthreads();

  for (int w = 0; w < W; ++w) {
    const int base = w << 6;
    const int n = min(64, M - base);
    if (t < 64) {
      if (t < n) {
        float a = sx1[base + t], b = sy1[base + t];
        float c = sx2[base + t], d = sy2[base + t];
        wx1[t] = a; wy1[t] = b; wx2[t] = c; wy2[t] = d;
        warea[t] = (c - a + 1.0f) * (d - b + 1.0f);
      }
    } else if (t < 128) {
      inrow[t - 64] = 0ull;
    }
    __syncthreads();
    {
      int r = t & 63, seg = t >> 6;
      unsigned long long bits = 0ull;
      if (r < n) {
        float ax1 = wx1[r], ay1 = wy1[r], ax2 = wx2[r], ay2 = wy2[r];
        float aarea = warea[r];
        for (int c = seg * 4; c < seg * 4 + 4; ++c) {
          if (c > r && c < n) {
            float xx1 = fmaxf(ax1, wx1[c]);
            float yy1 = fmaxf(ay1, wy1[c]);
            float xx2 = fminf(ax2, wx2[c]);
            float yy2 = fminf(ay2, wy2[c]);
            float ww = fmaxf(xx2 - xx1 + 1.0f, 0.0f);
            float hh = fmaxf(yy2 - yy1 + 1.0f, 0.0f);
            float inter = ww * hh;
            float iou = inter / (aarea + warea[c] - inter);
            if (iou > NMS_TH) bits |= (1ull << c);
          }
        }
      }
      if (bits) atomicOr(&inrow[r], bits);
    }
    __syncthreads();
    if (t < 64) {
      unsigned long long wordmask = (n >= 64) ? ~0ull : ((1ull << n) - 1ull);
      unsigned long long pending = (~sup[w]) & wordmask;
      unsigned long long kept = 0ull;
      while (pending) {
        int i = __builtin_ctzll(pending);
        kept |= (1ull << i);
        pending &= ~(inrow[i] | (1ull << i));
      }
      if (t == 0) keptmask_sh = kept;
      if (t < n && ((kept >> t) & 1ull)) keepflag[sorig[base + t]] = 1u;
    }
    __syncthreads();
    unsigned long long km = keptmask_sh;
    if (km) {
      int wid = t >> 6, lane = t & 63;
      for (int jw = w + 1 + wid; (jw << 6) < M; jw += 16) {
        int j = (jw << 6) + lane;
        bool supj = false;
        if (j < M) {
          float jx1 = sx1[j], jy1 = sy1[j], jx2 = sx2[j], jy2 = sy2[j];
          float jarea = (jx2 - jx1 + 1.0f) * (jy2 - jy1 + 1.0f);
          unsigned long long mm = km;
          while (mm) {
            int r = __builtin_ctzll(mm);
            mm &= mm - 1ull;
            float xx1 = fmaxf(wx1[r], jx1);
            float yy1 = fmaxf(wy1[r], jy1);
            float xx2 = fminf(wx2[r], jx2);
            float yy2 = fminf(wy2[r], jy2);
            float ww = fmaxf(xx2 - xx1 + 1.0f, 0.0f);
            float hh = fmaxf(yy2 - yy1 + 1.0f, 0.0f);
            float inter = ww * hh;
            float iou = inter / (warea[r] + jarea - inter);
            if (iou > NMS_TH) { supj = true; break; }
          }
        }
        unsigned long long bal = __ballot(supj);
        if (lane == 0 && bal) atomicOr(&sup[jw], bal);
      }
    }
    __syncthreads();
  }
}

// ---------------------------------------------------------------- output ----
// (fallback path only)
__global__ void output_kernel(const float* __restrict__ dx1, const float* __restrict__ dy1,
                              const float* __restrict__ dx2, const float* __restrict__ dy2,
                              const float* __restrict__ dsc,
                              const unsigned int* __restrict__ keepflag,
                              float* __restrict__ out) {
#pragma clang fp contract(off)
  int gid = blockIdx.x * blockDim.x + threadIdx.x;
  if (gid >= N_TOTAL) return;
  float f = keepflag[gid] ? 1.0f : 0.0f;
  out[gid * 5 + 0] = dx1[gid] * f;
  out[gid * 5 + 1] = dy1[gid] * f;
  out[gid * 5 + 2] = dx2[gid] * f;
  out[gid * 5 + 3] = dy2[gid] * f;
  out[gid * 5 + 4] = dsc[gid] * f;
}

// ---------------------------------------------------------------- launch ----
extern "C" void kernel_launch(void* const* d_in, const int* in_sizes, int n_in,
                              void* d_out, int out_size, void* d_ws, size_t ws_size,
                              hipStream_t stream) {
  (void)in_sizes; (void)n_in; (void)out_size;

  Inputs in;
  for (int i = 0; i < 6; ++i) {
    in.cls[i] = (const float*)d_in[2 * i];
    in.reg[i] = (const float*)d_in[2 * i + 1];
  }

  char* ws = (char*)d_ws;
  size_t o = 0;
  float* dx1 = (float*)(ws + o); o += (size_t)NA * 4;
  float* dy1 = (float*)(ws + o); o += (size_t)NA * 4;
  float* dx2 = (float*)(ws + o); o += (size_t)NA * 4;
  float* dy2 = (float*)(ws + o); o += (size_t)NA * 4;
  float* dsc = (float*)(ws + o); o += (size_t)NA * 4;
  unsigned long long* ckey = (unsigned long long*)(ws + o); o += (size_t)NA * 8;
  float* sx1 = (float*)(ws + o); o += (size_t)NA * 4;
  float* sy1 = (float*)(ws + o); o += (size_t)NA * 4;
  float* sx2 = (float*)(ws + o); o += (size_t)NA * 4;
  float* sy2 = (float*)(ws + o); o += (size_t)NA * 4;
  unsigned int* sorig = (unsigned int*)(ws + o); o += (size_t)NA * 4;
  unsigned int* keepflag = (unsigned int*)(ws + o); o += (size_t)NA * 4;
  unsigned int* rank32 = (unsigned int*)(ws + o); o += (size_t)NA * 4;
  unsigned int* cnt = (unsigned int*)(ws + o); o += (size_t)NA * 4;
  unsigned int* Mc = (unsigned int*)(ws + o); o += 64;
  o = (o + 511) & ~(size_t)511;
  unsigned long long* diag = (unsigned long long*)(ws + o); o += (size_t)NA * 8;
  unsigned long long* bandT = (unsigned long long*)(ws + o); o += (size_t)NBAND * NA * 8;
  unsigned long long* rlBits = (unsigned long long*)(ws + o); o += (size_t)TOT_ENT * 8;
  unsigned short* rlJw = (unsigned short*)(ws + o); o += (size_t)TOT_ENT * 2;
  size_t need = o;                            // ~41 MiB
  const bool fast = (need <= ws_size);        // ws_size constant -> graph-safe

  const int nb = (N_TOTAL + 255) / 256;  // 86

  if (fast) {
    (void)hipMemsetAsync((void*)Mc, 0, 64, stream);
    decode_kernel<<<nb, 256, 0, stream>>>(in, dx1, dy1, dx2, dy2, dsc, ckey, Mc,
                                          rank32, cnt, (float*)d_out);
    rank_kernel<<<dim3(nb, NSLICE), 256, 0, stream>>>(ckey, Mc, dx1, dy1, dx2, dy2,
                                                      sx1, sy1, sx2, sy2, sorig,
                                                      rank32);
    pairs_kernel<<<dim3(22, W_MAX), 1024, 0, stream>>>(sx1, sy1, sx2, sy2, Mc,
                                                       diag, bandT, cnt, rlJw, rlBits);
    scan_kernel<<<1, SCAN_T, 0, stream>>>(diag, bandT, cnt, rlJw, rlBits, sorig, Mc,
                                          dx1, dy1, dx2, dy2, dsc, (float*)d_out);
  } else {
    // fallback: zero keepflag + rank32 + cnt + Mc (contiguous)
    (void)hipMemsetAsync((void*)keepflag, 0, (size_t)NA * 12 + 64, stream);
    decode_kernel<<<nb, 256, 0, stream>>>(in, dx1, dy1, dx2, dy2, dsc, ckey, Mc,
                                          rank32, cnt, (float*)d_out);
    rank_kernel<<<dim3(nb, NSLICE), 256, 0, stream>>>(ckey, Mc, dx1, dy1, dx2, dy2,
                                                      sx1, sy1, sx2, sy2, sorig,
                                                      rank32);
    nms_kernel<<<1, 1024, 0, stream>>>(sx1, sy1, sx2, sy2, sorig, Mc, keepflag);
    output_kernel<<<nb, 256, 0, stream>>>(dx1, dy1, dx2, dy2, dsc, keepflag,
                                          (float*)d_out);
  }
}

// Round 4
// 260.848 us; speedup vs baseline: 1.3311x; 1.0047x over previous
//
#include <hip/hip_runtime.h>
#include <stdint.h>

#define N_TOTAL 21840
#define NA      21888          // N_TOTAL rounded up to multiple of 64
#define W_MAX   342            // ceil(21840/64)
#define TOT_ENT 3753792u       // 64 * (342*343/2)  triangular CSR capacity
#define NMS_TH  0.3f
#define FINAL_TH 0.5f
#define NSLICE  8              // rank range-split factor
#define SLOTS   11             // CSR slots per row handled by pusher lanes
#define SCAN_T  768            // scan block: 1 scanner wave + 11 pusher waves
#define NPUSH   11             // pusher wave count (SCAN_T/64 - 1)
#define GRP     4              // words per scan group
#define NBAND   7              // 2*GRP-1 transposed band arrays
#define GMAX    86             // max groups = ceil(W_MAX/GRP)

struct Inputs { const float* cls[6]; const float* reg[6]; };

// Raw barrier: drains LDS (lgkmcnt) but NOT vmem (vmcnt) — lets prefetched
// global loads stay in flight across the barrier.
__device__ __forceinline__ void block_bar() {
  asm volatile("s_waitcnt lgkmcnt(0)\n\ts_barrier" ::: "memory");
}

// Closed-form CSR row base: row r (sorted pos) owns 342-(r>>6) slots.
__device__ __forceinline__ unsigned rowbase_u(unsigned r) {
  unsigned w = r >> 6, l = r & 63u;
  return 64u * (342u * w - (w * (w - 1u)) / 2u) + l * (342u - w);
}

// ---------------------------------------------------------------- decode ----
__global__ void decode_kernel(Inputs in,
                              float* __restrict__ dx1, float* __restrict__ dy1,
                              float* __restrict__ dx2, float* __restrict__ dy2,
                              float* __restrict__ dsc,
                              unsigned long long* __restrict__ ckey,
                              unsigned int* __restrict__ Mc,
                              unsigned int* __restrict__ rank32,
                              unsigned int* __restrict__ cnt,
                              float* __restrict__ out) {
#pragma clang fp contract(off)
  int gid = blockIdx.x * blockDim.x + threadIdx.x;
  if (gid >= N_TOTAL) return;

  rank32[gid] = 0u;                       // zeroed ahead of rank_kernel
  cnt[gid] = 0u;                          // CSR row counts
  if (gid < NA - N_TOTAL) cnt[N_TOTAL + gid] = 0u;   // tail rows

  int sc, local;
  if      (gid < 16384) { sc = 0; local = gid;         }
  else if (gid < 20480) { sc = 1; local = gid - 16384; }
  else if (gid < 21504) { sc = 2; local = gid - 20480; }
  else if (gid < 21760) { sc = 3; local = gid - 21504; }
  else if (gid < 21824) { sc = 4; local = gid - 21760; }
  else                  { sc = 5; local = gid - 21824; }

  const int Wd     = 128 >> sc;
  const int stride = 4 << sc;
  const int HW     = Wd * Wd;
  const int x = local & (Wd - 1);
  const int y = local >> (7 - sc);

  const float* cls = in.cls[sc];
  const float* reg = in.reg[sc];

  float c0 = cls[local];
  float c1 = cls[HW + local];
  float m  = fmaxf(c0, c1);
  float e0 = expf(c0 - m);
  float e1 = expf(c1 - m);
  float prob = e1 / (e0 + e1);

  float l0 = reg[local];
  float l1 = reg[HW + local];
  float l2 = reg[2 * HW + local];
  float l3 = reg[3 * HW + local];

  float sF  = (float)stride;
  float pcx = 0.5f * sF + (float)x * sF;
  float pcy = 0.5f * sF + (float)y * sF;
  float pwh = sF * 4.0f;

  float cx = pcx + ((l0 * 0.1f) * pwh);
  float cy = pcy + ((l1 * 0.1f) * pwh);
  float w  = pwh * expf(l2 * 0.2f);
  float h  = pwh * expf(l3 * 0.2f);
  float x1 = cx - w * 0.5f;
  float y1 = cy - h * 0.5f;
  float x2 = x1 + w;
  float y2 = y1 + h;

  dx1[gid] = x1; dy1[gid] = y1; dx2[gid] = x2; dy2[gid] = y2; dsc[gid] = prob;

  // zero the output row; scan_kernel scatters kept rows afterwards
  out[gid * 5 + 0] = 0.0f;
  out[gid * 5 + 1] = 0.0f;
  out[gid * 5 + 2] = 0.0f;
  out[gid * 5 + 3] = 0.0f;
  out[gid * 5 + 4] = 0.0f;

  // Only boxes with score > FINAL_TH can affect the output (suppression only
  // flows downward in score order, and only >FINAL_TH rows are exposed).
  if (prob > FINAL_TH) {
    unsigned int pos = atomicAdd(Mc, 1u);
    ckey[pos] = ((unsigned long long)__float_as_uint(prob) << 32) |
                (unsigned int)(~(unsigned int)gid);
  }
}

// ---------------------------------------------------------------- rank ------
// Count-rank with 8-way key-range split; packed atomicAdd join.
__global__ void __launch_bounds__(256)
rank_kernel(const unsigned long long* __restrict__ ckey,
            const unsigned int* __restrict__ Mc,
            const float* __restrict__ dx1, const float* __restrict__ dy1,
            const float* __restrict__ dx2, const float* __restrict__ dy2,
            float* __restrict__ sx1, float* __restrict__ sy1,
            float* __restrict__ sx2, float* __restrict__ sy2,
            unsigned int* __restrict__ sorig,
            unsigned int* __restrict__ rank32) {
  __shared__ unsigned long long tile[256];
  const unsigned int M = *Mc;
  if (blockIdx.x * 256u >= M) return;          // uniform per block
  const int t = (int)threadIdx.x;
  const int p = (int)blockIdx.x * 256 + t;
  unsigned long long mykey = (p < (int)M) ? ckey[p] : 0ull;
  const int S  = (int)((M + NSLICE - 1) / NSLICE);
  const int lo = (int)blockIdx.y * S;
  const int hi = min((int)M, lo + S);
  int partial = 0;
  const int nt = (hi > lo) ? ((hi - lo + 255) >> 8) : 0;
  for (int ti = 0; ti < nt; ++ti) {
    int j = lo + ti * 256 + t;
    tile[t] = (j < hi) ? ckey[j] : 0ull;       // 0 never > any real key
    __syncthreads();
#pragma unroll 8
    for (int q = 0; q < 256; ++q) partial += (tile[q] > mykey) ? 1 : 0;
    __syncthreads();
  }
  if (p < (int)M) {
    unsigned int pack = (unsigned int)partial | (1u << 24);
    unsigned int old  = atomicAdd(&rank32[p], pack);
    unsigned int newv = old + pack;
    if ((newv >> 24) == NSLICE) {              // last slice to land scatters
      int r = (int)(newv & 0xFFFFFF);
      unsigned int orig = ~(unsigned int)(mykey & 0xffffffffull);
      sx1[r] = dx1[orig];
      sy1[r] = dy1[orig];
      sx2[r] = dx2[orig];
      sy2[r] = dy2[orig];
      sorig[r] = orig;
    }
  }
}

// ---------------------------------------------------------------- pairs -----
// Sparse suppression structure for GROUPED scan (group = GRP words):
//   diag[r]        = FULL symmetric in-word neighborhood of r (masked at use)
//   bandT[d-1][r]  = boxes of word (rw-d) overlapping box r, d = 1..7,
//                    materialized iff group(rw-d) >= group(rw)-1 (else unused)
//   CSR rows       = rlJw/rlBits[rowbase(r)+k], k < cnt[r], for
//                    group(cw) >= group(rw)+2 ONLY (inline bands cover rest)
__global__ void __launch_bounds__(1024)
pairs_kernel(const float* __restrict__ sx1, const float* __restrict__ sy1,
             const float* __restrict__ sx2, const float* __restrict__ sy2,
             const unsigned int* __restrict__ Mc,
             unsigned long long* __restrict__ diag,
             unsigned long long* __restrict__ bandT,
             unsigned int* __restrict__ cnt,
             unsigned short* __restrict__ rlJw,
             unsigned long long* __restrict__ rlBits) {
#pragma clang fp contract(off)
  const int M = (int)*Mc;
  const int W = (M + 63) >> 6;
  const int rw = (int)blockIdx.y;
  const int cwg = (int)blockIdx.x << 4;
  if (rw >= W || cwg >= W || cwg + 22 < rw) return;   // need cw >= rw-7

  const int t = (int)threadIdx.x;
  const int g = t >> 6, l = t & 63;
  const int cw = cwg + g;

  __shared__ float cx1[1024], cy1[1024], cx2[1024], cy2[1024], car[1024];
  {
    int c = (cw << 6) + l;
    if (cw < W && c < M) {
      float a = sx1[c], b = sy1[c], d = sx2[c], e = sy2[c];
      cx1[t] = a; cy1[t] = b; cx2[t] = d; cy2[t] = e;
      car[t] = (d - a + 1.0f) * (e - b + 1.0f);
    }
  }
  __syncthreads();
  if (cw >= W) return;
  const int rwg = rw >> 2, cg = cw >> 2;
  const bool isDiag = (cw == rw);
  const bool isBand = (cw < rw) && (cg >= rwg - 1);
  const bool isCsr  = (cg >= rwg + 2);
  if (!isDiag && !isBand && !isCsr) return;

  const int r = (rw << 6) + l;
  unsigned long long bits = 0ull;
  if (r < M) {
    float ax1 = sx1[r], ay1 = sy1[r], ax2 = sx2[r], ay2 = sy2[r];
    float aarea = (ax2 - ax1 + 1.0f) * (ay2 - ay1 + 1.0f);
    const int cmax = min(64, M - (cw << 6));
    const int sb = g << 6;
    // No cg>r test: diag keeps full symmetric bits (masked at use);
    // band zone is all-lower; CSR zone is all-higher.
    for (int cc = 0; cc < cmax; ++cc) {
      float xx1 = fmaxf(ax1, cx1[sb + cc]);
      float yy1 = fmaxf(ay1, cy1[sb + cc]);
      float xx2 = fminf(ax2, cx2[sb + cc]);
      float yy2 = fminf(ay2, cy2[sb + cc]);
      float ww = fmaxf(xx2 - xx1 + 1.0f, 0.0f);
      float hh = fmaxf(yy2 - yy1 + 1.0f, 0.0f);
      float inter = ww * hh;
      float iou = inter / (aarea + car[sb + cc] - inter);
      if (iou > NMS_TH) bits |= (1ull << cc);
    }
  }
  if (isDiag)      diag[r] = bits;
  else if (isBand) bandT[(size_t)(rw - cw - 1) * NA + r] = bits;
  else if (bits != 0ull) {                       // CSR: group dist >= 2
    unsigned k = atomicAdd(&cnt[r], 1u);
    unsigned b = rowbase_u((unsigned)r) + k;     // capacity 342-rw suffices
    rlJw[b]   = (unsigned short)cw;
    rlBits[b] = bits;
  }
}

// ---------------------------------------------------------------- scan ------
// Single-block greedy scan, DECOUPLED producer/consumer, no steady-state
// barrier. Dependency is loose: scanner group s needs pusher sources <= s-2
// applied (CSR is group-distance >= 2); pushers need only kmls[g].
//   sflag (scanner->pushers): groups published; lgkmcnt(0) before the write
//     makes kmls visible first; single-writer, monotone.
//   gdone[g] (pushers->scanner): per-GROUP completion counter. Each wave
//     processes groups in order and atomicAdd's gdone[s] AFTER lgkmcnt(0)
//     drains its sup atomics, so gdone[s-2]==NPUSH is EXACT: every wave has
//     applied every source group <= s-2. (R3 bug: an AGGREGATE counter
//     pflag>=11*(s-1) let 10 fast waves mask one straggler whose pending
//     edges target group s — nondeterministic wrong results. Per-group
//     counter restores the min-over-waves semantics the barrier provided.)
// No circular wait: scanner published s-1 before pushers need it at s-2.
__global__ void __launch_bounds__(SCAN_T)
scan_kernel(const unsigned long long* __restrict__ diag,
            const unsigned long long* __restrict__ bandT,
            const unsigned int* __restrict__ cnt,
            const unsigned short* __restrict__ rlJw,
            const unsigned long long* __restrict__ rlBits,
            const unsigned int* __restrict__ sorig,
            const unsigned int* __restrict__ Mc,
            const float* __restrict__ dx1, const float* __restrict__ dy1,
            const float* __restrict__ dx2, const float* __restrict__ dy2,
            const float* __restrict__ dsc,
            float* __restrict__ out) {
  __shared__ unsigned long long sup[W_MAX];
  __shared__ unsigned long long kmls[W_MAX];
  __shared__ unsigned gdone[GMAX];      // per-group pusher completions
  __shared__ volatile unsigned sflag;   // groups published by scanner
  const int t = (int)threadIdx.x;
  const int g = t >> 6, l = t & 63;
  const int M = (int)*Mc;
  const int W = (M + 63) >> 6;
  const int NS = (W + 3) >> 2;

  for (int i = t; i < W_MAX; i += SCAN_T) { sup[i] = 0ull; kmls[i] = 0ull; }
  for (int i = t; i < GMAX; i += SCAN_T) gdone[i] = 0u;
  if (t == 0) sflag = 0u;
  block_bar();

  if (g == 0) {
    // -------- scanner wave (critical path) --------
    __builtin_amdgcn_s_setprio(1);
    const unsigned long long lowm = (1ull << l) - 1ull;  // bits strictly < l
    unsigned long long dc[4], dn[4];                 // diag, cur / next group
    unsigned long long bc[4][NBAND], bn[4][NBAND];   // bands (d<=i+4 only)
    unsigned long long kp[4] = {0ull, 0ull, 0ull, 0ull};
#pragma unroll
    for (int i = 0; i < 4; ++i) {
      int v = i, vc = (v < W) ? v : 0;
      dc[i] = diag[(vc << 6) + l];
#pragma unroll
      for (int d = 1; d <= NBAND; ++d)
        if (d <= i + 4) bc[i][d - 1] = bandT[(size_t)(d - 1) * NA + (vc << 6) + l];
    }
#pragma unroll
    for (int i = 0; i < 4; ++i) {
      int v = 4 + i, vc = (v < W) ? v : 0;
      dn[i] = diag[(vc << 6) + l];
#pragma unroll
      for (int d = 1; d <= NBAND; ++d)
        if (d <= i + 4) bn[i][d - 1] = bandT[(size_t)(d - 1) * NA + (vc << 6) + l];
    }
    for (int s = 0; s < NS; ++s) {
      const int v0 = s << 2;
      // hoist prev-group incoming accumulators (independent of sup / kc)
      unsigned long long accp[4];
#pragma unroll
      for (int i = 0; i < 4; ++i) {
        unsigned long long a = 0ull;
#pragma unroll
        for (int d = 1; d <= NBAND; ++d)
          if (d <= i + 4 && d > i) a |= (bc[i][d - 1] & kp[i - d + 4]);
        accp[i] = a;
      }
      // gate: EVERY wave has applied all source groups <= s-2 (exact)
      if (s >= 2) {
        while (*(volatile unsigned*)&gdone[s - 2] < (unsigned)NPUSH) {}
        asm volatile("" ::: "memory");
      }
      unsigned long long sv[4];
#pragma unroll
      for (int i = 0; i < 4; ++i)
        sv[i] = (v0 + i < W) ? sup[v0 + i] : 0ull;
      unsigned long long kc[4];
#pragma unroll
      for (int i = 0; i < 4; ++i) {
        const int v = v0 + i;
        unsigned long long kept = 0ull;
        if (v < W) {
          unsigned long long acc = accp[i];
#pragma unroll
          for (int d = 1; d <= 3; ++d)
            if (d <= i) acc |= (bc[i][d - 1] & kc[i - d]);
          unsigned long long incoming = __ballot(acc != 0ull);
          const int n = min(64, M - (v << 6));
          unsigned long long wm = (n >= 64) ? ~0ull : ((1ull << n) - 1ull);
          unsigned long long pend = (~(sv[i] | incoming)) & wm;
          // ballot fixed-point: lowest undecided lane always decides
          const unsigned long long dv = dc[i] & lowm;
          unsigned long long dead = ~pend, und = pend;
          while (und) {
            unsigned long long bS = __ballot((dv & kept) != 0ull) & und;
            unsigned long long bK = __ballot((dv & ~dead) == 0ull) & und;
            kept |= bK; dead |= bS; und &= ~(bK | bS);
          }
          if (l == i) kmls[v] = kept;
        }
        kc[i] = kept;
      }
      // publish group s (kmls writes drained first; wave-level lgkmcnt)
      asm volatile("s_waitcnt lgkmcnt(0)" ::: "memory");
      if (l == 0) sflag = (unsigned)(s + 1);
      // rotate pipelines; issue loads for group s+2
#pragma unroll
      for (int i = 0; i < 4; ++i) kp[i] = kc[i];
#pragma unroll
      for (int i = 0; i < 4; ++i) {
        dc[i] = dn[i];
#pragma unroll
        for (int d = 0; d < NBAND; ++d)
          if (d <= i + 3) bc[i][d] = bn[i][d];
      }
      const int vn = v0 + 8;
#pragma unroll
      for (int i = 0; i < 4; ++i) {
        int v = vn + i, vc = (v < W) ? v : 0;
        dn[i] = diag[(vc << 6) + l];
#pragma unroll
        for (int d = 1; d <= NBAND; ++d)
          if (d <= i + 4) bn[i][d - 1] = bandT[(size_t)(d - 1) * NA + (vc << 6) + l];
      }
    }
    __builtin_amdgcn_s_setprio(0);
  } else {
    // -------- pusher lanes: 704 = 64 rows x 11 slots, 4 words per group ----
    const int p = (g - 1) * 64 + l;
    const int jrow = p / SLOTS;          // row within word, 0..63
    const int sub  = p % SLOTS;          // CSR slot 0..SLOTS-1
    unsigned cc[4], nc[4];               // cnt, current / next group
    unsigned long long cb[4], nb[4];     // bits
    unsigned cj[4], nj[4];               // jw
    // prologue: group 0 -> cur, group 1 -> next (clamped, unpredicated;
    // garbage unused: apply is predicated by jrow-kept and sub < cnt)
#pragma unroll
    for (int i = 0; i < 4; ++i) {
      int w = i, wc = (w < W) ? w : 0;
      cc[i] = cnt[(wc << 6) + jrow];
      unsigned idx = rowbase_u((unsigned)((wc << 6) + jrow)) + sub;
      if (idx >= TOT_ENT) idx = 0;
      cb[i] = rlBits[idx]; cj[i] = (unsigned)rlJw[idx];
    }
#pragma unroll
    for (int i = 0; i < 4; ++i) {
      int w = 4 + i, wc = (w < W) ? w : 0;
      nc[i] = cnt[(wc << 6) + jrow];
      unsigned idx = rowbase_u((unsigned)((wc << 6) + jrow)) + sub;
      if (idx >= TOT_ENT) idx = 0;
      nb[i] = rlBits[idx]; nj[i] = (unsigned)rlJw[idx];
    }
    for (int s = 0; s < NS; ++s) {
      // wait for scanner to publish group s (sleep: don't steal issue slots)
      while (sflag < (unsigned)(s + 1)) __builtin_amdgcn_s_sleep(1);
      asm volatile("" ::: "memory");
      const int v0 = s << 2;
#pragma unroll
      for (int i = 0; i < 4; ++i) {
        const int w = v0 + i;
        const unsigned long long km = (w < W) ? kmls[w] : 0ull;
        if ((km >> jrow) & 1ull) {
          if (sub < (int)cc[i]) atomicOr(&sup[cj[i]], cb[i]);
          if (cc[i] > (unsigned)SLOTS) {   // rare high-degree tail
            unsigned rb_ = rowbase_u((unsigned)((w << 6) + jrow));
            for (int k = sub + SLOTS; k < (int)cc[i]; k += SLOTS) {
              unsigned ii2 = rb_ + k;
              atomicOr(&sup[rlJw[ii2]], rlBits[ii2]);
            }
          }
        }
      }
      // publish completion of source group s (sup atomics drained first)
      asm volatile("s_waitcnt lgkmcnt(0)" ::: "memory");
      if (l == 0) atomicAdd(&gdone[s], 1u);
      // rotate; issue loads for group s+2
#pragma unroll
      for (int i = 0; i < 4; ++i) { cc[i] = nc[i]; cb[i] = nb[i]; cj[i] = nj[i]; }
      const int w0 = v0 + 8;
#pragma unroll
      for (int i = 0; i < 4; ++i) {
        int w = w0 + i, wc = (w < W) ? w : 0;
        nc[i] = cnt[(wc << 6) + jrow];
        unsigned idx = rowbase_u((unsigned)((wc << 6) + jrow)) + sub;
        if (idx >= TOT_ENT) idx = 0;
        nb[i] = rlBits[idx]; nj[i] = (unsigned)rlJw[idx];
      }
    }
  }
  block_bar();

  // scatter kept rows into the (pre-zeroed) output
  for (int i = t; i < (W << 6); i += SCAN_T) {
    if ((kmls[i >> 6] >> (i & 63)) & 1ull) {
      unsigned int orig = sorig[i];
      out[(size_t)orig * 5 + 0] = dx1[orig];
      out[(size_t)orig * 5 + 1] = dy1[orig];
      out[(size_t)orig * 5 + 2] = dx2[orig];
      out[(size_t)orig * 5 + 3] = dy2[orig];
      out[(size_t)orig * 5 + 4] = dsc[orig];
    }
  }
}

// ------------------------------------------------- fallback NMS (tiny ws) ---
__global__ void __launch_bounds__(1024)
nms_kernel(const float* __restrict__ sx1, const float* __restrict__ sy1,
           const float* __restrict__ sx2, const float* __restrict__ sy2,
           const unsigned int* __restrict__ sorig,
           const unsigned int* __restrict__ Mc,
           unsigned int* __restrict__ keepflag) {
#pragma clang fp contract(off)
  __shared__ unsigned long long sup[W_MAX];
  __shared__ unsigned long long inrow[64];
  __shared__ float wx1[64], wy1[64], wx2[64], wy2[64], warea[64];
  __shared__ unsigned long long keptmask_sh;

  const int t = (int)threadIdx.x;
  const int M = (int)*Mc;
  const int W = (M + 63) >> 6;

  for (int i = t; i < W_MAX; i += 1024) sup[i] = 0ull;
  __syncthreads();

  for (int w = 0; w < W; ++w) {
    const int base = w << 6;
    const int n = min(64, M - base);
    if (t < 64) {
      if (t < n) {
        float a = sx1[base + t], b = sy1[base + t];
        float c = sx2[base + t], d = sy2[base + t];
        wx1[t] = a; wy1[t] = b; wx2[t] = c; wy2[t] = d;
        warea[t] = (c - a + 1.0f) * (d - b + 1.0f);
      }
    } else if (t < 128) {
      inrow[t - 64] = 0ull;
    }
    __syncthreads();
    {
      int r = t & 63, seg = t >> 6;
      unsigned long long bits = 0ull;
      if (r < n) {
        float ax1 = wx1[r], ay1 = wy1[r], ax2 = wx2[r], ay2 = wy2[r];
        float aarea = warea[r];
        for (int c = seg * 4; c < seg * 4 + 4; ++c) {
          if (c > r && c < n) {
            float xx1 = fmaxf(ax1, wx1[c]);
            float yy1 = fmaxf(ay1, wy1[c]);
            float xx2 = fminf(ax2, wx2[c]);
            float yy2 = fminf(ay2, wy2[c]);
            float ww = fmaxf(xx2 - xx1 + 1.0f, 0.0f);
            float hh = fmaxf(yy2 - yy1 + 1.0f, 0.0f);
            float inter = ww * hh;
            float iou = inter / (aarea + warea[c] - inter);
            if (iou > NMS_TH) bits |= (1ull << c);
          }
        }
      }
      if (bits) atomicOr(&inrow[r], bits);
    }
    __syncthreads();
    if (t < 64) {
      unsigned long long wordmask = (n >= 64) ? ~0ull : ((1ull << n) - 1ull);
      unsigned long long pending = (~sup[w]) & wordmask;
      unsigned long long kept = 0ull;
      while (pending) {
        int i = __builtin_ctzll(pending);
        kept |= (1ull << i);
        pending &= ~(inrow[i] | (1ull << i));
      }
      if (t == 0) keptmask_sh = kept;
      if (t < n && ((kept >> t) & 1ull)) keepflag[sorig[base + t]] = 1u;
    }
    __syncthreads();
    unsigned long long km = keptmask_sh;
    if (km) {
      int wid = t >> 6, lane = t & 63;
      for (int jw = w + 1 + wid; (jw << 6) < M; jw += 16) {
        int j = (jw << 6) + lane;
        bool supj = false;
        if (j < M) {
          float jx1 = sx1[j], jy1 = sy1[j], jx2 = sx2[j], jy2 = sy2[j];
          float jarea = (jx2 - jx1 + 1.0f) * (jy2 - jy1 + 1.0f);
          unsigned long long mm = km;
          while (mm) {
            int r = __builtin_ctzll(mm);
            mm &= mm - 1ull;
            float xx1 = fmaxf(wx1[r], jx1);
            float yy1 = fmaxf(wy1[r], jy1);
            float xx2 = fminf(wx2[r], jx2);
            float yy2 = fminf(wy2[r], jy2);
            float ww = fmaxf(xx2 - xx1 + 1.0f, 0.0f);
            float hh = fmaxf(yy2 - yy1 + 1.0f, 0.0f);
            float inter = ww * hh;
            float iou = inter / (warea[r] + jarea - inter);
            if (iou > NMS_TH) { supj = true; break; }
          }
        }
        unsigned long long bal = __ballot(supj);
        if (lane == 0 && bal) atomicOr(&sup[jw], bal);
      }
    }
    __syncthreads();
  }
}

// ---------------------------------------------------------------- output ----
// (fallback path only)
__global__ void output_kernel(const float* __restrict__ dx1, const float* __restrict__ dy1,
                              const float* __restrict__ dx2, const float* __restrict__ dy2,
                              const float* __restrict__ dsc,
                              const unsigned int* __restrict__ keepflag,
                              float* __restrict__ out) {
#pragma clang fp contract(off)
  int gid = blockIdx.x * blockDim.x + threadIdx.x;
  if (gid >= N_TOTAL) return;
  float f = keepflag[gid] ? 1.0f : 0.0f;
  out[gid * 5 + 0] = dx1[gid] * f;
  out[gid * 5 + 1] = dy1[gid] * f;
  out[gid * 5 + 2] = dx2[gid] * f;
  out[gid * 5 + 3] = dy2[gid] * f;
  out[gid * 5 + 4] = dsc[gid] * f;
}

// ---------------------------------------------------------------- launch ----
extern "C" void kernel_launch(void* const* d_in, const int* in_sizes, int n_in,
                              void* d_out, int out_size, void* d_ws, size_t ws_size,
                              hipStream_t stream) {
  (void)in_sizes; (void)n_in; (void)out_size;

  Inputs in;
  for (int i = 0; i < 6; ++i) {
    in.cls[i] = (const float*)d_in[2 * i];
    in.reg[i] = (const float*)d_in[2 * i + 1];
  }

  char* ws = (char*)d_ws;
  size_t o = 0;
  float* dx1 = (float*)(ws + o); o += (size_t)NA * 4;
  float* dy1 = (float*)(ws + o); o += (size_t)NA * 4;
  float* dx2 = (float*)(ws + o); o += (size_t)NA * 4;
  float* dy2 = (float*)(ws + o); o += (size_t)NA * 4;
  float* dsc = (float*)(ws + o); o += (size_t)NA * 4;
  unsigned long long* ckey = (unsigned long long*)(ws + o); o += (size_t)NA * 8;
  float* sx1 = (float*)(ws + o); o += (size_t)NA * 4;
  float* sy1 = (float*)(ws + o); o += (size_t)NA * 4;
  float* sx2 = (float*)(ws + o); o += (size_t)NA * 4;
  float* sy2 = (float*)(ws + o); o += (size_t)NA * 4;
  unsigned int* sorig = (unsigned int*)(ws + o); o += (size_t)NA * 4;
  unsigned int* keepflag = (unsigned int*)(ws + o); o += (size_t)NA * 4;
  unsigned int* rank32 = (unsigned int*)(ws + o); o += (size_t)NA * 4;
  unsigned int* cnt = (unsigned int*)(ws + o); o += (size_t)NA * 4;
  unsigned int* Mc = (unsigned int*)(ws + o); o += 64;
  o = (o + 511) & ~(size_t)511;
  unsigned long long* diag = (unsigned long long*)(ws + o); o += (size_t)NA * 8;
  unsigned long long* bandT = (unsigned long long*)(ws + o); o += (size_t)NBAND * NA * 8;
  unsigned long long* rlBits = (unsigned long long*)(ws + o); o += (size_t)TOT_ENT * 8;
  unsigned short* rlJw = (unsigned short*)(ws + o); o += (size_t)TOT_ENT * 2;
  size_t need = o;                            // ~41 MiB
  const bool fast = (need <= ws_size);        // ws_size constant -> graph-safe

  const int nb = (N_TOTAL + 255) / 256;  // 86

  if (fast) {
    (void)hipMemsetAsync((void*)Mc, 0, 64, stream);
    decode_kernel<<<nb, 256, 0, stream>>>(in, dx1, dy1, dx2, dy2, dsc, ckey, Mc,
                                          rank32, cnt, (float*)d_out);
    rank_kernel<<<dim3(nb, NSLICE), 256, 0, stream>>>(ckey, Mc, dx1, dy1, dx2, dy2,
                                                      sx1, sy1, sx2, sy2, sorig,
                                                      rank32);
    pairs_kernel<<<dim3(22, W_MAX), 1024, 0, stream>>>(sx1, sy1, sx2, sy2, Mc,
                                                       diag, bandT, cnt, rlJw, rlBits);
    scan_kernel<<<1, SCAN_T, 0, stream>>>(diag, bandT, cnt, rlJw, rlBits, sorig, Mc,
                                          dx1, dy1, dx2, dy2, dsc, (float*)d_out);
  } else {
    // fallback: zero keepflag + rank32 + cnt + Mc (contiguous)
    (void)hipMemsetAsync((void*)keepflag, 0, (size_t)NA * 12 + 64, stream);
    decode_kernel<<<nb, 256, 0, stream>>>(in, dx1, dy1, dx2, dy2, dsc, ckey, Mc,
                                          rank32, cnt, (float*)d_out);
    rank_kernel<<<dim3(nb, NSLICE), 256, 0, stream>>>(ckey, Mc, dx1, dy1, dx2, dy2,
                                                      sx1, sy1, sx2, sy2, sorig,
                                                      rank32);
    nms_kernel<<<1, 1024, 0, stream>>>(sx1, sy1, sx2, sy2, sorig, Mc, keepflag);
    output_kernel<<<nb, 256, 0, stream>>>(dx1, dy1, dx2, dy2, dsc, keepflag,
                                          (float*)d_out);
  }
}